// Round 5
// baseline (2182.913 us; speedup 1.0000x reference)
//
#include <hip/hip_runtime.h>
#include <stdint.h>
#include <stddef.h>

#define T_ 512
#define B_ 128
#define D_ 256
#define H_ 256
#define NR 768
#define OUT_MAIN 33554432ull // B*T*2H
#define XT_STRIDE 12288      // u16 per (wg,t) slot (24 KB)
#define HOUT_OFF 8192        // u16 offset of compact-h region within slot
#define HB 280               // h LDS row stride in u16

typedef __attribute__((ext_vector_type(4))) float f32x4;
typedef __attribute__((ext_vector_type(8))) short s16x8;
typedef __attribute__((ext_vector_type(4))) uint32_t u32x4;
typedef __attribute__((ext_vector_type(2))) uint32_t u32x2;

__device__ __forceinline__ unsigned short f2bf(float f) {
    union { float f; uint32_t u; } v; v.f = f;
    return (unsigned short)((v.u + 0x7FFFu + ((v.u >> 16) & 1u)) >> 16);
}
__device__ __forceinline__ float lo16(uint32_t w) {
    union { uint32_t u; float f; } v; v.u = w << 16; return v.f;
}
__device__ __forceinline__ float hi16(uint32_t w) {
    union { uint32_t u; float f; } v; v.u = w & 0xffff0000u; return v.f;
}
__device__ __forceinline__ uint32_t cvtpk(float a, float b) {
    uint32_t r;
    asm("v_cvt_pk_bf16_f32 %0, %1, %2" : "=v"(r) : "v"(a), "v"(b));
    return r;
}
__device__ __forceinline__ float sigm(float x) {
    return __builtin_amdgcn_rcpf(1.f + __expf(-x));
}
__device__ __forceinline__ float tanh_(float x) {
    float e = __expf(2.f * x);
    return 1.f - 2.f * __builtin_amdgcn_rcpf(e + 1.f);
}
__device__ __forceinline__ s16x8 pack8(const float* f) {
    union { s16x8 v; unsigned short u[8]; } p;
#pragma unroll
    for (int i = 0; i < 8; ++i) p.u[i] = f2bf(f[i]);
    return p.v;
}

// ---------------- kernel 0: convert w_ih (fw|bw) to bf16 ----------------
__global__ void k_convert(const float* __restrict__ wf, const float* __restrict__ wb,
                          unsigned short* __restrict__ dst) {
    int i = blockIdx.x * blockDim.x + threadIdx.x;
    const int n = NR * D_;
    if (i < n) dst[i] = f2bf(wf[i]);
    else if (i < 2 * n) dst[i] = f2bf(wb[i - n]);
}

// ---------------- kernel 1: XT = x @ w_ih^T + bias, recur-lane layout, coalesced ----
__global__ __launch_bounds__(512, 2) void k_xgemm(
    const float* __restrict__ x, const unsigned short* __restrict__ wbf,
    const float* __restrict__ bih_f, const float* __restrict__ bhh_f,
    const float* __restrict__ bih_b, const float* __restrict__ bhh_b,
    unsigned short* __restrict__ XT)
{
    __shared__ __align__(16) unsigned short lds_a[32 * 72];
    __shared__ __align__(16) unsigned short xt_l[2 * XT_STRIDE];
    const int tid = threadIdx.x, lane = tid & 63, wn = tid >> 6;
    const int t = blockIdx.x;
    const int dir = blockIdx.y >> 2, q2 = blockIdx.y & 3;

    f32x4 acc[2][6];
#pragma unroll
    for (int m = 0; m < 2; ++m)
#pragma unroll
        for (int n = 0; n < 6; ++n) acc[m][n] = (f32x4){0.f, 0.f, 0.f, 0.f};

    for (int kb = 0; kb < 4; ++kb) {
        if (kb) __syncthreads();
        {
            int row = tid >> 4, c4 = (tid & 15) * 4;
            const float* src = x + ((size_t)(q2 * 32 + row) * T_ + t) * D_ + kb * 64 + c4;
            f32x4 f = *(const f32x4*)src;
            u32x2 p = { cvtpk(f[0], f[1]), cvtpk(f[2], f[3]) };
            *(u32x2*)&lds_a[row * 72 + c4] = p;
        }
        __syncthreads();
#pragma unroll
        for (int kt = 0; kt < 2; ++kt) {
            s16x8 av[2];
#pragma unroll
            for (int mt = 0; mt < 2; ++mt) {
                int r = mt * 16 + (lane & 15);
                av[mt] = *(const s16x8*)&lds_a[r * 72 + kt * 32 + (lane >> 4) * 8];
            }
#pragma unroll
            for (int nt = 0; nt < 6; ++nt) {
                int c = dir * NR + wn * 96 + nt * 16 + (lane & 15);
                s16x8 bv = *(const s16x8*)(wbf + (size_t)c * D_ + kb * 64 + kt * 32 + (lane >> 4) * 8);
#pragma unroll
                for (int mt = 0; mt < 2; ++mt)
                    acc[mt][nt] = __builtin_amdgcn_mfma_f32_16x16x32_bf16(av[mt], bv, acc[mt][nt], 0, 0, 0);
            }
        }
    }
    const float* bih = dir ? bih_b : bih_f;
    const float* bhh = dir ? bhh_b : bhh_f;
    __syncthreads();
#pragma unroll
    for (int nt = 0; nt < 6; ++nt) {
        const int cw = wn * 96 + nt * 16 + (lane & 15);
        const int gate = cw >> 8, j = cw & 255;
        const int jt = (j >> 4) & 1;
        const int rtid = (j >> 5) * 64 + ((lane >> 4) << 4) + (j & 15);
        float bias = bih[cw] + (cw < 512 ? bhh[cw] : 0.f);
#pragma unroll
        for (int mt = 0; mt < 2; ++mt) {
#pragma unroll
            for (int q = 0; q < 4; ++q) {
                int v = (jt * 4 + q) * 3 + gate;
                xt_l[mt * XT_STRIDE + rtid * 24 + v] = f2bf(acc[mt][nt][q] + bias);
            }
        }
    }
    __syncthreads();
#pragma unroll
    for (int half = 0; half < 2; ++half) {
        size_t base = ((size_t)(dir * 8 + q2 * 2 + half) * T_ + t) * XT_STRIDE;
#pragma unroll
        for (int k = 0; k < 3; ++k)
            *(u32x4*)(XT + base + (size_t)tid * 24 + k * 8)
                = *(const u32x4*)&xt_l[half * XT_STRIDE + tid * 24 + k * 8];
    }
}

// ---------------- kernel 2: recurrence; h stores batched per 4-step chunk ----------
template<int SP, bool DUMP>
__device__ __forceinline__ void gru_step(
    int s, int dir, int tid, int lane, int wid,
    const unsigned short* __restrict__ XTw, unsigned short* __restrict__ HO,
    unsigned short* hb, const s16x8 (&fB)[6][8], float bhn0, float bhn1,
    u32x4 (&CUR)[3], u32x4 (&NXT)[3], float (&hreg)[8], u32x4 (&pkh)[4])
{
    const int sn = (s < T_ - 1) ? s + 1 : s;
    const int tn = dir ? (T_ - 1 - sn) : sn;
    {   // prefetch xT(t+1) into registers (3 x dwordx4)
        const u32x4* p = (const u32x4*)(XTw + (size_t)tn * XT_STRIDE) + (size_t)tid * 3;
        NXT[0] = p[0]; NXT[1] = p[1]; NXT[2] = p[2];
    }
    const unsigned short* hr = hb + (SP & 1) * (16 * HB);
    unsigned short*       hw = hb + ((SP & 1) ^ 1) * (16 * HB);

    s16x8 a[8];
#pragma unroll
    for (int k0 = 0; k0 < 8; ++k0)
        a[k0] = *(const s16x8*)&hr[(lane & 15) * HB + k0 * 32 + (lane >> 4) * 8];

    f32x4 acc[6];
#pragma unroll
    for (int n = 0; n < 6; ++n) acc[n] = (f32x4){0.f, 0.f, 0.f, 0.f};
#pragma unroll
    for (int k0 = 0; k0 < 8; ++k0) {
#pragma unroll
        for (int nt = 0; nt < 6; ++nt)
            acc[nt] = __builtin_amdgcn_mfma_f32_16x16x32_bf16(a[k0], fB[nt][k0], acc[nt], 0, 0, 0);
    }

    float hn[8];
#pragma unroll
    for (int jt = 0; jt < 2; ++jt) {
        const float bn = jt ? bhn1 : bhn0;
#pragma unroll
        for (int q = 0; q < 4; ++q) {
            const int idx = jt * 4 + q;
            const int v = idx * 3;
            uint32_t w0 = CUR[(v)     >> 3][((v)     >> 1) & 3];
            uint32_t w1 = CUR[(v + 1) >> 3][((v + 1) >> 1) & 3];
            uint32_t w2 = CUR[(v + 2) >> 3][((v + 2) >> 1) & 3];
            float xr = (v & 1)       ? hi16(w0) : lo16(w0);
            float xz = ((v + 1) & 1) ? hi16(w1) : lo16(w1);
            float xn = ((v + 2) & 1) ? hi16(w2) : lo16(w2);
            float rg = sigm(acc[jt][q] + xr);
            float zg = sigm(acc[2 + jt][q] + xz);
            float ng = tanh_(xn + rg * (acc[4 + jt][q] + bn));
            hn[idx] = ng + zg * (hreg[idx] - ng);
            hreg[idx] = hn[idx];
        }
    }
    // pack h -> bf16 pairs (held in registers; dumped once per chunk)
#pragma unroll
    for (int k = 0; k < 4; ++k) pkh[SP][k] = cvtpk(hn[2 * k], hn[2 * k + 1]);
#pragma unroll
    for (int k = 0; k < 4; ++k) {
        const int i0 = 2 * k;
        const int j = 32 * wid + (i0 >> 2) * 16 + (lane & 15);
        const int r0 = (lane >> 4) * 4 + (i0 & 3);
        hw[r0 * HB + j]       = (unsigned short)pkh[SP][k];
        hw[(r0 + 1) * HB + j] = (unsigned short)(pkh[SP][k] >> 16);
    }
    if constexpr (DUMP) {
        // burst-store the chunk's 4 packed h vectors (after this step's loads, so
        // subsequent steps' load retirement isn't queued behind store acks)
        const int sc = s - 3;
#pragma unroll
        for (int k = 0; k < 4; ++k) {
            const int tk = dir ? (T_ - 1 - (sc + k)) : (sc + k);
            *(u32x4*)(HO + (size_t)tk * XT_STRIDE + (size_t)tid * 8) = pkh[k];
        }
    }
    __builtin_amdgcn_sched_barrier(0);
    asm volatile("s_waitcnt lgkmcnt(0)");
    __builtin_amdgcn_s_barrier();
    __builtin_amdgcn_sched_barrier(0);
}

__global__ __launch_bounds__(512, 2) void k_recur(
    const float* __restrict__ whh_f, const float* __restrict__ whh_b,
    const float* __restrict__ bhh_f, const float* __restrict__ bhh_b,
    const unsigned short* __restrict__ XT, unsigned short* __restrict__ XT_hout)
{
    __shared__ __align__(16) unsigned short hb[2 * 16 * HB];
    const int tid = threadIdx.x, lane = tid & 63, wid = tid >> 6;
    const int bid = blockIdx.x;
    const int dir = bid >> 3;
    const float* whh = dir ? whh_b : whh_f;
    const float* bhh = dir ? bhh_b : bhh_f;

    s16x8 fB[6][8];
#pragma unroll
    for (int g = 0; g < 3; ++g) {
#pragma unroll
        for (int half = 0; half < 2; ++half) {
            int nt = 2 * g + half;
            int cb = g * 256 + 32 * wid + half * 16;
#pragma unroll
            for (int k0 = 0; k0 < 8; ++k0) {
                const float* sp = whh + (size_t)(cb + (lane & 15)) * H_ + k0 * 32 + (lane >> 4) * 8;
                float fv[8];
                *(f32x4*)&fv[0] = *(const f32x4*)(sp);
                *(f32x4*)&fv[4] = *(const f32x4*)(sp + 4);
                fB[nt][k0] = pack8(fv);
            }
        }
    }
    const float bhn0 = bhh[512 + 32 * wid + (lane & 15)];
    const float bhn1 = bhh[512 + 32 * wid + 16 + (lane & 15)];

    for (int i = tid; i < 16 * HB / 2; i += 512) ((uint32_t*)hb)[i] = 0;
    __syncthreads();

    const unsigned short* XTw = XT + (size_t)bid * T_ * XT_STRIDE;
    unsigned short* HO = XT_hout + (size_t)bid * T_ * XT_STRIDE + HOUT_OFF;
    u32x4 XA[3], XB[3], pkh[4];
    float hreg[8];
#pragma unroll
    for (int i = 0; i < 8; ++i) hreg[i] = 0.f;
    {
        const int t0 = dir ? (T_ - 1) : 0;
        const u32x4* p = (const u32x4*)(XTw + (size_t)t0 * XT_STRIDE) + (size_t)tid * 3;
        XA[0] = p[0]; XA[1] = p[1]; XA[2] = p[2];
    }
#pragma unroll 1
    for (int s = 0; s < T_; s += 4) {
        gru_step<0, false>(s,     dir, tid, lane, wid, XTw, HO, hb, fB, bhn0, bhn1, XA, XB, hreg, pkh);
        gru_step<1, false>(s + 1, dir, tid, lane, wid, XTw, HO, hb, fB, bhn0, bhn1, XB, XA, hreg, pkh);
        gru_step<2, false>(s + 2, dir, tid, lane, wid, XTw, HO, hb, fB, bhn0, bhn1, XA, XB, hreg, pkh);
        gru_step<3, true >(s + 3, dir, tid, lane, wid, XTw, HO, hb, fB, bhn0, bhn1, XB, XA, hreg, pkh);
    }
}

// ---------------- kernel 3: scatter compact h -> out (+ h_last) ----------------
__global__ __launch_bounds__(512) void k_scatter(const unsigned short* __restrict__ XT,
                                                 float* __restrict__ out) {
    const int tid = threadIdx.x, lane = tid & 63, wid = tid >> 6;
    const int t = blockIdx.x & 511, wg = blockIdx.x >> 9;
    const int dir = wg >> 3, b0 = (wg & 7) * 16;
    u32x4 v = *((const u32x4*)(XT + ((size_t)wg * T_ + t) * XT_STRIDE + HOUT_OFF) + tid);
    const bool last = (t == (dir ? 0 : T_ - 1));
#pragma unroll
    for (int k = 0; k < 4; ++k) {
#pragma unroll
        for (int half = 0; half < 2; ++half) {
            const int idx = 2 * k + half;
            const int q = idx & 3, jt = idx >> 2;
            const int row = (lane >> 4) * 4 + q;
            const int j = 32 * wid + jt * 16 + (lane & 15);
            const int b = b0 + row;
            float val = half ? hi16(v[k]) : lo16(v[k]);
            out[((size_t)b * T_ + t) * 512 + (size_t)dir * 256 + j] = val;
            if (last)
                out[OUT_MAIN + (size_t)dir * B_ * H_ + (size_t)b * H_ + j] = val;
        }
    }
}

extern "C" void kernel_launch(void* const* d_in, const int* in_sizes, int n_in,
                              void* d_out, int out_size, void* d_ws, size_t ws_size,
                              hipStream_t stream) {
    const float* x     = (const float*)d_in[0];
    const float* wih_f = (const float*)d_in[1];
    const float* whh_f = (const float*)d_in[2];
    const float* bih_f = (const float*)d_in[3];
    const float* bhh_f = (const float*)d_in[4];
    const float* wih_b = (const float*)d_in[5];
    const float* whh_b = (const float*)d_in[6];
    const float* bih_b = (const float*)d_in[7];
    const float* bhh_b = (const float*)d_in[8];
    float* out = (float*)d_out;

    unsigned short* wbf = (unsigned short*)d_ws;
    unsigned short* XT  = (unsigned short*)((char*)d_ws + 786432);

    k_convert<<<dim3(768), dim3(512), 0, stream>>>(wih_f, wih_b, wbf);
    k_xgemm<<<dim3(512, 8), dim3(512), 0, stream>>>(x, wbf, bih_f, bhh_f, bih_b, bhh_b, XT);
    k_recur<<<dim3(16), dim3(512), 0, stream>>>(whh_f, whh_b, bhh_f, bhh_b, XT, XT);
    k_scatter<<<dim3(16 * 512), dim3(512), 0, stream>>>(XT, out);
}

// Round 6
// 2105.128 us; speedup vs baseline: 1.0370x; 1.0370x over previous
//
#include <hip/hip_runtime.h>
#include <stdint.h>
#include <stddef.h>

#define T_ 512
#define B_ 128
#define D_ 256
#define H_ 256
#define NR 768
#define OUT_MAIN 33554432ull // B*T*2H
#define XT_STRIDE 12288      // u16 per (wg,t) slot: 1024 threads * 12 values
#define HB 280               // h LDS row stride in u16

typedef __attribute__((ext_vector_type(4))) float f32x4;
typedef __attribute__((ext_vector_type(8))) short s16x8;
typedef __attribute__((ext_vector_type(4))) uint32_t u32x4;
typedef __attribute__((ext_vector_type(2))) uint32_t u32x2;

__device__ __forceinline__ unsigned short f2bf(float f) {
    union { float f; uint32_t u; } v; v.f = f;
    return (unsigned short)((v.u + 0x7FFFu + ((v.u >> 16) & 1u)) >> 16);
}
__device__ __forceinline__ float lo16(uint32_t w) {
    union { uint32_t u; float f; } v; v.u = w << 16; return v.f;
}
__device__ __forceinline__ float hi16(uint32_t w) {
    union { uint32_t u; float f; } v; v.u = w & 0xffff0000u; return v.f;
}
__device__ __forceinline__ uint32_t cvtpk(float a, float b) {
    uint32_t r;
    asm("v_cvt_pk_bf16_f32 %0, %1, %2" : "=v"(r) : "v"(a), "v"(b));
    return r;
}
__device__ __forceinline__ float sigm(float x) {
    return __builtin_amdgcn_rcpf(1.f + __expf(-x));
}
__device__ __forceinline__ float tanh_(float x) {
    float e = __expf(2.f * x);
    return 1.f - 2.f * __builtin_amdgcn_rcpf(e + 1.f);
}
__device__ __forceinline__ s16x8 pack8(const float* f) {
    union { s16x8 v; unsigned short u[8]; } p;
#pragma unroll
    for (int i = 0; i < 8; ++i) p.u[i] = f2bf(f[i]);
    return p.v;
}

// ---------------- kernel 0: convert w_ih (fw|bw) to bf16 ----------------
__global__ void k_convert(const float* __restrict__ wf, const float* __restrict__ wb,
                          unsigned short* __restrict__ dst) {
    int i = blockIdx.x * blockDim.x + threadIdx.x;
    const int n = NR * D_;
    if (i < n) dst[i] = f2bf(wf[i]);
    else if (i < 2 * n) dst[i] = f2bf(wb[i - n]);
}

// ---------------- kernel 1: XT = x @ w_ih^T + bias, 1024-thread recur-lane layout ----
// grid (T_, 8): y = dir*4 + q2. Rows q2*32..+32 (M=32), N=768, K=256. 512 threads.
__global__ __launch_bounds__(512, 2) void k_xgemm(
    const float* __restrict__ x, const unsigned short* __restrict__ wbf,
    const float* __restrict__ bih_f, const float* __restrict__ bhh_f,
    const float* __restrict__ bih_b, const float* __restrict__ bhh_b,
    unsigned short* __restrict__ XT)
{
    __shared__ __align__(16) unsigned short lds_a[32 * 72];
    __shared__ __align__(16) unsigned short xt_l[2 * XT_STRIDE];
    const int tid = threadIdx.x, lane = tid & 63, wn = tid >> 6;
    const int t = blockIdx.x;
    const int dir = blockIdx.y >> 2, q2 = blockIdx.y & 3;

    f32x4 acc[2][6];
#pragma unroll
    for (int m = 0; m < 2; ++m)
#pragma unroll
        for (int n = 0; n < 6; ++n) acc[m][n] = (f32x4){0.f, 0.f, 0.f, 0.f};

    for (int kb = 0; kb < 4; ++kb) {
        if (kb) __syncthreads();
        {
            int row = tid >> 4, c4 = (tid & 15) * 4;
            const float* src = x + ((size_t)(q2 * 32 + row) * T_ + t) * D_ + kb * 64 + c4;
            f32x4 f = *(const f32x4*)src;
            u32x2 p = { cvtpk(f[0], f[1]), cvtpk(f[2], f[3]) };
            *(u32x2*)&lds_a[row * 72 + c4] = p;
        }
        __syncthreads();
#pragma unroll
        for (int kt = 0; kt < 2; ++kt) {
            s16x8 av[2];
#pragma unroll
            for (int mt = 0; mt < 2; ++mt) {
                int r = mt * 16 + (lane & 15);
                av[mt] = *(const s16x8*)&lds_a[r * 72 + kt * 32 + (lane >> 4) * 8];
            }
#pragma unroll
            for (int nt = 0; nt < 6; ++nt) {
                int c = dir * NR + wn * 96 + nt * 16 + (lane & 15);
                s16x8 bv = *(const s16x8*)(wbf + (size_t)c * D_ + kb * 64 + kt * 32 + (lane >> 4) * 8);
#pragma unroll
                for (int mt = 0; mt < 2; ++mt)
                    acc[mt][nt] = __builtin_amdgcn_mfma_f32_16x16x32_bf16(av[mt], bv, acc[mt][nt], 0, 0, 0);
            }
        }
    }
    const float* bih = dir ? bih_b : bih_f;
    const float* bhh = dir ? bhh_b : bhh_f;
    __syncthreads();
#pragma unroll
    for (int nt = 0; nt < 6; ++nt) {
        const int cw = wn * 96 + nt * 16 + (lane & 15);
        const int gate = cw >> 8, j = cw & 255;
        const int tid_r = (j >> 4) * 64 + ((lane >> 4) << 4) + (j & 15);
        float bias = bih[cw] + (cw < 512 ? bhh[cw] : 0.f);
#pragma unroll
        for (int mt = 0; mt < 2; ++mt) {
#pragma unroll
            for (int q = 0; q < 4; ++q) {
                int v = q * 3 + gate;
                xt_l[mt * XT_STRIDE + tid_r * 12 + v] = f2bf(acc[mt][nt][q] + bias);
            }
        }
    }
    __syncthreads();
#pragma unroll
    for (int half = 0; half < 2; ++half) {
        size_t base = ((size_t)(dir * 8 + q2 * 2 + half) * T_ + t) * XT_STRIDE;
#pragma unroll
        for (int k = 0; k < 3; ++k)
            *(u32x4*)(XT + base + (size_t)tid * 24 + k * 8)
                = *(const u32x4*)&xt_l[half * XT_STRIDE + tid * 24 + k * 8];
    }
}

// ---------------- kernel 2: recurrence, 1024 threads, fB = 96 regs/wave ----------
template<int P>
__device__ __forceinline__ void gru_step(
    int s, int dir, int b0, int tid, int lane, int wid,
    const unsigned short* __restrict__ XTw, float* __restrict__ out,
    unsigned short* hb, const s16x8 (&fB)[3][8], float bn,
    u32x2 (&CUR)[3], u32x2 (&NXT)[3], float (&hreg)[4])
{
    const int t  = dir ? (T_ - 1 - s) : s;
    const int sn = (s < T_ - 1) ? s + 1 : s;
    const int tn = dir ? (T_ - 1 - sn) : sn;
    {   // prefetch xT(t+1) into registers (3 x dwordx2)
        const u32x2* p = (const u32x2*)(XTw + (size_t)tn * XT_STRIDE) + (size_t)tid * 3;
        NXT[0] = p[0]; NXT[1] = p[1]; NXT[2] = p[2];
    }
    const unsigned short* hr = hb + P * (16 * HB);
    unsigned short*       hw = hb + (P ^ 1) * (16 * HB);

    s16x8 a[8];
#pragma unroll
    for (int k0 = 0; k0 < 8; ++k0)
        a[k0] = *(const s16x8*)&hr[(lane & 15) * HB + k0 * 32 + (lane >> 4) * 8];

    f32x4 acc[3];
#pragma unroll
    for (int g = 0; g < 3; ++g) acc[g] = (f32x4){0.f, 0.f, 0.f, 0.f};
#pragma unroll
    for (int k0 = 0; k0 < 8; ++k0) {
#pragma unroll
        for (int g = 0; g < 3; ++g)
            acc[g] = __builtin_amdgcn_mfma_f32_16x16x32_bf16(a[k0], fB[g][k0], acc[g], 0, 0, 0);
    }

    const int j = 16 * wid + (lane & 15);
    float hn[4];
#pragma unroll
    for (int q = 0; q < 4; ++q) {
        const int v = q * 3;
        uint32_t w0 = CUR[(v)     >> 2][((v)     >> 1) & 1];
        uint32_t w1 = CUR[(v + 1) >> 2][((v + 1) >> 1) & 1];
        uint32_t w2 = CUR[(v + 2) >> 2][((v + 2) >> 1) & 1];
        float xr = (v & 1)       ? hi16(w0) : lo16(w0);
        float xz = ((v + 1) & 1) ? hi16(w1) : lo16(w1);
        float xn = ((v + 2) & 1) ? hi16(w2) : lo16(w2);
        float rg = sigm(acc[0][q] + xr);
        float zg = sigm(acc[1][q] + xz);
        float ng = tanh_(xn + rg * (acc[2][q] + bn));
        hn[q] = ng + zg * (hreg[q] - ng);
        hreg[q] = hn[q];
    }
    // h_new -> LDS (4 scalar u16 writes) and out (4 f32 stores), r2 ordering
#pragma unroll
    for (int q = 0; q < 4; ++q) {
        const int row = (lane >> 4) * 4 + q;
        hw[row * HB + j] = (unsigned short)cvtpk(hn[q], hn[q]);
        out[((size_t)(b0 + row) << 18) + ((size_t)t << 9) + (size_t)dir * 256 + j] = hn[q];
    }
    if (s == T_ - 1) {
#pragma unroll
        for (int q = 0; q < 4; ++q) {
            const int row = (lane >> 4) * 4 + q;
            out[OUT_MAIN + (size_t)dir * B_ * H_ + (size_t)(b0 + row) * H_ + j] = hn[q];
        }
    }
    __builtin_amdgcn_sched_barrier(0);
    asm volatile("s_waitcnt lgkmcnt(0)");
    __builtin_amdgcn_s_barrier();
    __builtin_amdgcn_sched_barrier(0);
}

__global__ __launch_bounds__(1024, 4) void k_recur(
    const float* __restrict__ whh_f, const float* __restrict__ whh_b,
    const float* __restrict__ bhh_f, const float* __restrict__ bhh_b,
    const unsigned short* __restrict__ XT,
    float* __restrict__ out)
{
    __shared__ __align__(16) unsigned short hb[2 * 16 * HB];
    const int tid = threadIdx.x, lane = tid & 63, wid = tid >> 6;
    const int bid = blockIdx.x;
    const int dir = bid >> 3, b0 = (bid & 7) * 16;
    const float* whh = dir ? whh_b : whh_f;
    const float* bhh = dir ? bhh_b : bhh_f;

    const int j = 16 * wid + (lane & 15);
    // stationary w_hh fragments: 24 x s16x8 = 96 regs/lane
    s16x8 fB[3][8];
#pragma unroll
    for (int g = 0; g < 3; ++g) {
#pragma unroll
        for (int k0 = 0; k0 < 8; ++k0) {
            const float* sp = whh + (size_t)(g * 256 + j) * H_ + k0 * 32 + (lane >> 4) * 8;
            float fv[8];
            *(f32x4*)&fv[0] = *(const f32x4*)(sp);
            *(f32x4*)&fv[4] = *(const f32x4*)(sp + 4);
            fB[g][k0] = pack8(fv);
        }
    }
    const float bn = bhh[512 + j];

    for (int i = tid; i < 16 * HB / 2; i += 1024) ((uint32_t*)hb)[i] = 0;
    __syncthreads();

    const unsigned short* XTw = XT + (size_t)bid * T_ * XT_STRIDE;
    u32x2 XA[3], XB[3];
    float hreg[4];
#pragma unroll
    for (int i = 0; i < 4; ++i) hreg[i] = 0.f;
    {
        const int t0 = dir ? (T_ - 1) : 0;
        const u32x2* p = (const u32x2*)(XTw + (size_t)t0 * XT_STRIDE) + (size_t)tid * 3;
        XA[0] = p[0]; XA[1] = p[1]; XA[2] = p[2];
    }
#pragma unroll 1
    for (int s = 0; s < T_; s += 2) {
        gru_step<0>(s,     dir, b0, tid, lane, wid, XTw, out, hb, fB, bn, XA, XB, hreg);
        gru_step<1>(s + 1, dir, b0, tid, lane, wid, XTw, out, hb, fB, bn, XB, XA, hreg);
    }
}

extern "C" void kernel_launch(void* const* d_in, const int* in_sizes, int n_in,
                              void* d_out, int out_size, void* d_ws, size_t ws_size,
                              hipStream_t stream) {
    const float* x     = (const float*)d_in[0];
    const float* wih_f = (const float*)d_in[1];
    const float* whh_f = (const float*)d_in[2];
    const float* bih_f = (const float*)d_in[3];
    const float* bhh_f = (const float*)d_in[4];
    const float* wih_b = (const float*)d_in[5];
    const float* whh_b = (const float*)d_in[6];
    const float* bih_b = (const float*)d_in[7];
    const float* bhh_b = (const float*)d_in[8];
    float* out = (float*)d_out;

    unsigned short* wbf = (unsigned short*)d_ws;
    unsigned short* XT  = (unsigned short*)((char*)d_ws + 786432);

    k_convert<<<dim3(768), dim3(512), 0, stream>>>(wih_f, wih_b, wbf);
    k_xgemm<<<dim3(512, 8), dim3(512), 0, stream>>>(x, wbf, bih_f, bhh_f, bih_b, bhh_b, XT);
    k_recur<<<dim3(16), dim3(1024), 0, stream>>>(whh_f, whh_b, bhh_f, bhh_b, XT, out);
}

// Round 7
// 2016.577 us; speedup vs baseline: 1.0825x; 1.0439x over previous
//
#include <hip/hip_runtime.h>
#include <stdint.h>
#include <stddef.h>

#define T_ 512
#define B_ 128
#define D_ 256
#define H_ 256
#define NR 768
#define OUT_MAIN 33554432ull // B*T*2H
#define XT_STRIDE 12288      // u16 per (wg,t) slot: 512 threads * 24 values
#define HB 280               // h LDS row stride in u16

typedef __attribute__((ext_vector_type(4))) float f32x4;
typedef __attribute__((ext_vector_type(8))) short s16x8;
typedef __attribute__((ext_vector_type(4))) uint32_t u32x4;

__device__ __forceinline__ unsigned short f2bf(float f) {
    union { float f; uint32_t u; } v; v.f = f;
    return (unsigned short)((v.u + 0x7FFFu + ((v.u >> 16) & 1u)) >> 16);
}
__device__ __forceinline__ float bf2f(unsigned short h) {
    union { uint32_t u; float f; } v; v.u = ((uint32_t)h) << 16;
    return v.f;
}
__device__ __forceinline__ float lo16(uint32_t w) {
    union { uint32_t u; float f; } v; v.u = w << 16; return v.f;
}
__device__ __forceinline__ float hi16(uint32_t w) {
    union { uint32_t u; float f; } v; v.u = w & 0xffff0000u; return v.f;
}
__device__ __forceinline__ uint32_t cvt1bf(float x) {
    uint32_t r;
    asm("v_cvt_pk_bf16_f32 %0, %1, %2" : "=v"(r) : "v"(x), "v"(x));
    return r;
}
__device__ __forceinline__ float sigm(float x) {
    return __builtin_amdgcn_rcpf(1.f + __expf(-x));
}
__device__ __forceinline__ float tanh_(float x) {
    float e = __expf(2.f * x);
    return 1.f - 2.f * __builtin_amdgcn_rcpf(e + 1.f);
}
__device__ __forceinline__ s16x8 pack8(const float* f) {
    union { s16x8 v; unsigned short u[8]; } p;
#pragma unroll
    for (int i = 0; i < 8; ++i) p.u[i] = f2bf(f[i]);
    return p.v;
}

// ---------------- kernel 0: convert w_ih (fw|bw) to bf16 ----------------
__global__ void k_convert(const float* __restrict__ wf, const float* __restrict__ wb,
                          unsigned short* __restrict__ dst) {
    int i = blockIdx.x * blockDim.x + threadIdx.x;
    const int n = NR * D_;
    if (i < n) dst[i] = f2bf(wf[i]);
    else if (i < 2 * n) dst[i] = f2bf(wb[i - n]);
}

// ---------------- kernel 1: XT = x @ w_ih^T + bias (r1 tile, r2 layout) ----------
// tile: M=128 (one t, all b) x N=384, K=256 (BK=64). 8 waves as 2x4. grid (512,4).
__global__ __launch_bounds__(512, 2) void k_xgemm(
    const float* __restrict__ x, const unsigned short* __restrict__ wbf,
    const float* __restrict__ bih_f, const float* __restrict__ bhh_f,
    const float* __restrict__ bih_b, const float* __restrict__ bhh_b,
    unsigned short* __restrict__ XT)
{
    __shared__ __align__(16) unsigned short lds_a[128 * 72];
    const int tid = threadIdx.x;
    const int lane = tid & 63, wid = tid >> 6;
    const int wm = wid >> 2, wn = wid & 3;
    const int t = blockIdx.x;
    const int cblk = blockIdx.y * 384;

    f32x4 acc[4][6];
#pragma unroll
    for (int m = 0; m < 4; ++m)
#pragma unroll
        for (int n = 0; n < 6; ++n) acc[m][n] = (f32x4){0.f, 0.f, 0.f, 0.f};

    for (int kb = 0; kb < 4; ++kb) {
        if (kb) __syncthreads();
        {   // stage A tile (128 x 64) fp32->bf16 into LDS
            int row = tid >> 2, seg = tid & 3;
            const float* src = x + ((size_t)row * T_ + t) * D_ + kb * 64 + seg * 16;
            float fv[16];
            *(f32x4*)&fv[0]  = *(const f32x4*)(src);
            *(f32x4*)&fv[4]  = *(const f32x4*)(src + 4);
            *(f32x4*)&fv[8]  = *(const f32x4*)(src + 8);
            *(f32x4*)&fv[12] = *(const f32x4*)(src + 12);
            *(s16x8*)&lds_a[row * 72 + seg * 16]     = pack8(&fv[0]);
            *(s16x8*)&lds_a[row * 72 + seg * 16 + 8] = pack8(&fv[8]);
        }
        __syncthreads();
#pragma unroll
        for (int kt = 0; kt < 2; ++kt) {
            s16x8 av[4];
#pragma unroll
            for (int mt = 0; mt < 4; ++mt) {
                int r = wm * 64 + mt * 16 + (lane & 15);
                av[mt] = *(const s16x8*)&lds_a[r * 72 + kt * 32 + (lane >> 4) * 8];
            }
#pragma unroll
            for (int nt = 0; nt < 6; ++nt) {
                int c = cblk + wn * 96 + nt * 16 + (lane & 15);
                const unsigned short* bs = wbf + (size_t)c * D_ + kb * 64 + kt * 32 + (lane >> 4) * 8;
                s16x8 bv = *(const s16x8*)bs;
#pragma unroll
                for (int mt = 0; mt < 4; ++mt)
                    acc[mt][nt] = __builtin_amdgcn_mfma_f32_16x16x32_bf16(av[mt], bv, acc[mt][nt], 0, 0, 0);
            }
        }
    }
    // epilogue: bias + scatter into recur-lane XT layout
    const int dir = blockIdx.y >> 1;
    const float* bih = dir ? bih_b : bih_f;
    const float* bhh = dir ? bhh_b : bhh_f;
#pragma unroll
    for (int nt = 0; nt < 6; ++nt) {
        const int cw = (blockIdx.y & 1) * 384 + wn * 96 + nt * 16 + (lane & 15);
        const int gate = cw >> 8, j = cw & 255;
        const int jt = (j >> 4) & 1;
        const int wl = (j >> 5) * 64 + (j & 15);
        float bias = bih[cw] + (cw < 512 ? bhh[cw] : 0.f);
#pragma unroll
        for (int mt = 0; mt < 4; ++mt) {
#pragma unroll
            for (int q = 0; q < 4; ++q) {
                int rr = wm * 64 + mt * 16 + (lane >> 4) * 4 + q;
                int tid_r = wl + (((rr & 15) >> 2) << 4);
                size_t idx = ((size_t)(dir * 8 + (rr >> 4)) * T_ + t) * XT_STRIDE
                           + (size_t)tid_r * 24 + (size_t)((jt * 4 + q) * 3 + gate);
                XT[idx] = f2bf(acc[mt][nt][q] + bias);
            }
        }
    }
}

// ---------------- kernel 2: recurrence (r2 skeleton + hoisted addressing) ----------
template<int P>
__device__ __forceinline__ void gru_step(
    int s, int dir, int b0, int tid, int lane, int wid,
    const unsigned short* __restrict__ XTw, float* __restrict__ out,
    unsigned short* hb, const s16x8 (&fB)[6][8], float bhn0, float bhn1,
    u32x4 (&CUR)[3], u32x4 (&NXT)[3], const uint32_t (&ooff)[2][4])
{
    const int t  = dir ? (T_ - 1 - s) : s;
    const int sn = (s < T_ - 1) ? s + 1 : s;
    const int tn = dir ? (T_ - 1 - sn) : sn;
    {   // prefetch xT(t+1): uniform base (SGPR) + invariant thread offset
        const u32x4* p = (const u32x4*)(XTw + (size_t)tn * XT_STRIDE);
        NXT[0] = p[tid * 3]; NXT[1] = p[tid * 3 + 1]; NXT[2] = p[tid * 3 + 2];
    }
    const unsigned short* hr = hb + P * (16 * HB);
    unsigned short*       hw = hb + (P ^ 1) * (16 * HB);

    f32x4 acc[6];
#pragma unroll
    for (int n = 0; n < 6; ++n) acc[n] = (f32x4){0.f, 0.f, 0.f, 0.f};
#pragma unroll
    for (int k0 = 0; k0 < 8; ++k0) {
        s16x8 a = *(const s16x8*)&hr[(lane & 15) * HB + k0 * 32 + (lane >> 4) * 8];
#pragma unroll
        for (int nt = 0; nt < 6; ++nt)
            acc[nt] = __builtin_amdgcn_mfma_f32_16x16x32_bf16(a, fB[nt][k0], acc[nt], 0, 0, 0);
    }

    float* outT = out + ((size_t)t << 9);
#pragma unroll
    for (int jt = 0; jt < 2; ++jt) {
        const int j = 32 * wid + jt * 16 + (lane & 15);
        const float bn = jt ? bhn1 : bhn0;
#pragma unroll
        for (int q = 0; q < 4; ++q) {
            const int row = (lane >> 4) * 4 + q;
            const int v = (jt * 4 + q) * 3;
            uint32_t w0 = CUR[(v)     >> 3][((v)     >> 1) & 3];
            uint32_t w1 = CUR[(v + 1) >> 3][((v + 1) >> 1) & 3];
            uint32_t w2 = CUR[(v + 2) >> 3][((v + 2) >> 1) & 3];
            float xr = (v & 1)       ? hi16(w0) : lo16(w0);
            float xz = ((v + 1) & 1) ? hi16(w1) : lo16(w1);
            float xn = ((v + 2) & 1) ? hi16(w2) : lo16(w2);
            float hv = bf2f(hr[row * HB + j]);
            float rg = sigm(acc[jt][q] + xr);
            float zg = sigm(acc[2 + jt][q] + xz);
            float ng = tanh_(xn + rg * (acc[4 + jt][q] + bn));
            float hnew = ng + zg * (hv - ng);
            hw[row * HB + j] = (unsigned short)cvt1bf(hnew);
            *(float*)((char*)outT + ooff[jt][q]) = hnew;
            if (s == T_ - 1)
                out[OUT_MAIN + (size_t)dir * B_ * H_ + (size_t)(b0 + row) * H_ + j] = hnew;
        }
    }
    __builtin_amdgcn_sched_barrier(0);
    asm volatile("s_waitcnt lgkmcnt(0)");
    __builtin_amdgcn_s_barrier();
    __builtin_amdgcn_sched_barrier(0);
}

__global__ __launch_bounds__(512, 2) void k_recur(
    const float* __restrict__ whh_f, const float* __restrict__ whh_b,
    const float* __restrict__ bhh_f, const float* __restrict__ bhh_b,
    const unsigned short* __restrict__ XT,
    float* __restrict__ out)
{
    __shared__ __align__(16) unsigned short hb[2 * 16 * HB];
    const int tid = threadIdx.x, lane = tid & 63, wid = tid >> 6;
    const int bid = blockIdx.x;
    const int dir = bid >> 3, b0 = (bid & 7) * 16;
    const float* whh = dir ? whh_b : whh_f;
    const float* bhh = dir ? bhh_b : bhh_f;

    // stationary w_hh fragments: 48 x s16x8 = 192 regs/lane (VGPR+AGPR unified)
    s16x8 fB[6][8];
#pragma unroll
    for (int g = 0; g < 3; ++g) {
#pragma unroll
        for (int half = 0; half < 2; ++half) {
            int nt = 2 * g + half;
            int cb = g * 256 + 32 * wid + half * 16;
#pragma unroll
            for (int k0 = 0; k0 < 8; ++k0) {
                const float* sp = whh + (size_t)(cb + (lane & 15)) * H_ + k0 * 32 + (lane >> 4) * 8;
                float fv[8];
                *(f32x4*)&fv[0] = *(const f32x4*)(sp);
                *(f32x4*)&fv[4] = *(const f32x4*)(sp + 4);
                fB[nt][k0] = pack8(fv);
            }
        }
    }
    const float bhn0 = bhh[512 + 32 * wid + (lane & 15)];
    const float bhn1 = bhh[512 + 32 * wid + 16 + (lane & 15)];

    // hoisted per-thread out-store byte offsets (t-part is wave-uniform per step)
    uint32_t ooff[2][4];
#pragma unroll
    for (int jt = 0; jt < 2; ++jt)
#pragma unroll
        for (int q = 0; q < 4; ++q) {
            const int row = (lane >> 4) * 4 + q;
            const int j = 32 * wid + jt * 16 + (lane & 15);
            ooff[jt][q] = (uint32_t)(((((uint32_t)(b0 + row)) << 18)
                                      + (uint32_t)dir * 256u + (uint32_t)j) * 4u);
        }

    for (int i = tid; i < 16 * HB / 2; i += 512) ((uint32_t*)hb)[i] = 0;
    __syncthreads();

    const unsigned short* XTw = XT + (size_t)bid * T_ * XT_STRIDE;
    u32x4 XA[3], XB[3];
    {
        const int t0 = dir ? (T_ - 1) : 0;
        const u32x4* p = (const u32x4*)(XTw + (size_t)t0 * XT_STRIDE);
        XA[0] = p[tid * 3]; XA[1] = p[tid * 3 + 1]; XA[2] = p[tid * 3 + 2];
    }
#pragma unroll 1
    for (int s = 0; s < T_; s += 2) {
        gru_step<0>(s,     dir, b0, tid, lane, wid, XTw, out, hb, fB, bhn0, bhn1, XA, XB, ooff);
        gru_step<1>(s + 1, dir, b0, tid, lane, wid, XTw, out, hb, fB, bhn0, bhn1, XB, XA, ooff);
    }
}

extern "C" void kernel_launch(void* const* d_in, const int* in_sizes, int n_in,
                              void* d_out, int out_size, void* d_ws, size_t ws_size,
                              hipStream_t stream) {
    const float* x     = (const float*)d_in[0];
    const float* wih_f = (const float*)d_in[1];
    const float* whh_f = (const float*)d_in[2];
    const float* bih_f = (const float*)d_in[3];
    const float* bhh_f = (const float*)d_in[4];
    const float* wih_b = (const float*)d_in[5];
    const float* whh_b = (const float*)d_in[6];
    const float* bih_b = (const float*)d_in[7];
    const float* bhh_b = (const float*)d_in[8];
    float* out = (float*)d_out;

    unsigned short* wbf = (unsigned short*)d_ws;
    unsigned short* XT  = (unsigned short*)((char*)d_ws + 786432);

    k_convert<<<dim3(768), dim3(512), 0, stream>>>(wih_f, wih_b, wbf);
    k_xgemm<<<dim3(512, 4), dim3(512), 0, stream>>>(x, wbf, bih_f, bhh_f, bih_b, bhh_b, XT);
    k_recur<<<dim3(16), dim3(512), 0, stream>>>(whh_f, whh_b, bhh_f, bhh_b, XT, out);
}

// Round 8
// 1463.101 us; speedup vs baseline: 1.4920x; 1.3783x over previous
//
#include <hip/hip_runtime.h>
#include <stdint.h>
#include <stddef.h>

#define T_ 512
#define B_ 128
#define D_ 256
#define H_ 256
#define NR 768               // 3*H
#define OUT_MAIN 33554432ull // B*T*2H
#define XT_STRIDE 12288      // u16 per (wg, t): 512 threads * 24 values
#define HB 280               // hbuf row stride in u16

typedef __attribute__((ext_vector_type(4))) float f32x4;
typedef __attribute__((ext_vector_type(8))) short s16x8;
typedef __attribute__((ext_vector_type(4))) uint32_t u32x4;
typedef __attribute__((ext_vector_type(2))) uint32_t u32x2;

__device__ __forceinline__ unsigned short f2bf(float f) {
    union { float f; uint32_t u; } v; v.f = f;
    return (unsigned short)((v.u + 0x7FFFu + ((v.u >> 16) & 1u)) >> 16);
}
__device__ __forceinline__ float bf2f(unsigned short h) {
    union { uint32_t u; float f; } v; v.u = ((uint32_t)h) << 16;
    return v.f;
}
__device__ __forceinline__ uint32_t cvtpk(float a, float b) {
    uint32_t r;
    asm("v_cvt_pk_bf16_f32 %0, %1, %2" : "=v"(r) : "v"(a), "v"(b));
    return r;
}
__device__ __forceinline__ float sigm(float x) {
    return __builtin_amdgcn_rcpf(1.f + __expf(-x));
}
__device__ __forceinline__ float tanh_(float x) {
    float e = __expf(2.f * x);
    return 1.f - 2.f * __builtin_amdgcn_rcpf(e + 1.f);
}
__device__ __forceinline__ s16x8 pack8(const float* f) {
    union { s16x8 v; unsigned short u[8]; } p;
#pragma unroll
    for (int i = 0; i < 8; ++i) p.u[i] = f2bf(f[i]);
    return p.v;
}

// ---------------- kernel 0: convert w_ih (fw|bw) to bf16 ----------------
__global__ void k_convert(const float* __restrict__ wf, const float* __restrict__ wb,
                          unsigned short* __restrict__ dst) {
    int i = blockIdx.x * blockDim.x + threadIdx.x;
    const int n = NR * D_;
    if (i < n) dst[i] = f2bf(wf[i]);
    else if (i < 2 * n) dst[i] = f2bf(wb[i - n]);
}

// ---------------- kernel 1: XT = x @ w_ih^T + bias (round-4 version, verbatim) ----
// grid (T_, 8): y = dir*4 + q2. Rows q2*32..+32 (M=32), N=768, K=256.
__global__ __launch_bounds__(512, 2) void k_xgemm(
    const float* __restrict__ x, const unsigned short* __restrict__ wbf,
    const float* __restrict__ bih_f, const float* __restrict__ bhh_f,
    const float* __restrict__ bih_b, const float* __restrict__ bhh_b,
    unsigned short* __restrict__ XT)
{
    __shared__ __align__(16) unsigned short lds_a[32 * 72];
    __shared__ __align__(16) unsigned short xt_l[2 * XT_STRIDE];
    const int tid = threadIdx.x, lane = tid & 63, wn = tid >> 6;
    const int t = blockIdx.x;
    const int dir = blockIdx.y >> 2, q2 = blockIdx.y & 3;

    f32x4 acc[2][6];
#pragma unroll
    for (int m = 0; m < 2; ++m)
#pragma unroll
        for (int n = 0; n < 6; ++n) acc[m][n] = (f32x4){0.f, 0.f, 0.f, 0.f};

    for (int kb = 0; kb < 4; ++kb) {
        if (kb) __syncthreads();
        {   // stage A tile (32 rows x 64 k) fp32 -> bf16
            int row = tid >> 4, c4 = (tid & 15) * 4;
            const float* src = x + ((size_t)(q2 * 32 + row) * T_ + t) * D_ + kb * 64 + c4;
            f32x4 f = *(const f32x4*)src;
            u32x2 p = { cvtpk(f[0], f[1]), cvtpk(f[2], f[3]) };
            *(u32x2*)&lds_a[row * 72 + c4] = p;
        }
        __syncthreads();
#pragma unroll
        for (int kt = 0; kt < 2; ++kt) {
            s16x8 av[2];
#pragma unroll
            for (int mt = 0; mt < 2; ++mt) {
                int r = mt * 16 + (lane & 15);
                av[mt] = *(const s16x8*)&lds_a[r * 72 + kt * 32 + (lane >> 4) * 8];
            }
#pragma unroll
            for (int nt = 0; nt < 6; ++nt) {
                int c = dir * NR + wn * 96 + nt * 16 + (lane & 15);
                s16x8 bv = *(const s16x8*)(wbf + (size_t)c * D_ + kb * 64 + kt * 32 + (lane >> 4) * 8);
#pragma unroll
                for (int mt = 0; mt < 2; ++mt)
                    acc[mt][nt] = __builtin_amdgcn_mfma_f32_16x16x32_bf16(av[mt], bv, acc[mt][nt], 0, 0, 0);
            }
        }
    }
    // epilogue: bias, transpose to recur layout in LDS
    const float* bih = dir ? bih_b : bih_f;
    const float* bhh = dir ? bhh_b : bhh_f;
    __syncthreads();
#pragma unroll
    for (int nt = 0; nt < 6; ++nt) {
        const int cw = wn * 96 + nt * 16 + (lane & 15);
        const int gate = cw >> 8, j = cw & 255;
        const int jt = (j >> 4) & 1;
        const int rtid = (j >> 5) * 64 + ((lane >> 4) << 4) + (j & 15);
        float bias = bih[cw] + (cw < 512 ? bhh[cw] : 0.f);
#pragma unroll
        for (int mt = 0; mt < 2; ++mt) {
#pragma unroll
            for (int q = 0; q < 4; ++q) {
                int v = (jt * 4 + q) * 3 + gate;
                xt_l[mt * XT_STRIDE + rtid * 24 + v] = f2bf(acc[mt][nt][q] + bias);
            }
        }
    }
    __syncthreads();
    // coalesced global write: per half-tile 24 KB contiguous
#pragma unroll
    for (int half = 0; half < 2; ++half) {
        size_t base = ((size_t)(dir * 8 + q2 * 2 + half) * T_ + t) * XT_STRIDE;
#pragma unroll
        for (int k = 0; k < 3; ++k)
            *(u32x4*)(XT + base + (size_t)tid * 24 + k * 8)
                = *(const u32x4*)&xt_l[half * XT_STRIDE + tid * 24 + k * 8];
    }
}

// ---------------- kernel 2: recurrence (round-2 version, verbatim) ----------------
template<int P>
__device__ __forceinline__ void gru_step(
    int s, int dir, int b0, int tid, int lane, int wid,
    const unsigned short* __restrict__ XTw, float* __restrict__ out,
    unsigned short* hb, const s16x8 (&fB)[6][8], float bhn0, float bhn1,
    s16x8 (&CUR)[3], s16x8 (&NXT)[3])
{
    const int t  = dir ? (T_ - 1 - s) : s;
    const int sn = (s < T_ - 1) ? s + 1 : s;
    const int tn = dir ? (T_ - 1 - sn) : sn;
    {   // prefetch xT(t+1) into registers (3 x dwordx4), consumed next step
        const s16x8* p = (const s16x8*)(XTw + (size_t)tn * XT_STRIDE) + (size_t)tid * 3;
        NXT[0] = p[0]; NXT[1] = p[1]; NXT[2] = p[2];
    }
    const unsigned short* hr = hb + P * (16 * HB);
    unsigned short*       hw = hb + (P ^ 1) * (16 * HB);

    f32x4 acc[6];
#pragma unroll
    for (int n = 0; n < 6; ++n) acc[n] = (f32x4){0.f, 0.f, 0.f, 0.f};
#pragma unroll
    for (int k0 = 0; k0 < 8; ++k0) {
        s16x8 a = *(const s16x8*)&hr[(lane & 15) * HB + k0 * 32 + (lane >> 4) * 8];
#pragma unroll
        for (int nt = 0; nt < 6; ++nt)
            acc[nt] = __builtin_amdgcn_mfma_f32_16x16x32_bf16(a, fB[nt][k0], acc[nt], 0, 0, 0);
    }
#pragma unroll
    for (int jt = 0; jt < 2; ++jt) {
        const int j = 32 * wid + jt * 16 + (lane & 15);
        const float bn = jt ? bhn1 : bhn0;
#pragma unroll
        for (int q = 0; q < 4; ++q) {
            const int row = (lane >> 4) * 4 + q;
            const int v = (jt * 4 + q) * 3;
            float xr = bf2f((unsigned short)CUR[(v + 0) >> 3][(v + 0) & 7]);
            float xz = bf2f((unsigned short)CUR[(v + 1) >> 3][(v + 1) & 7]);
            float xn = bf2f((unsigned short)CUR[(v + 2) >> 3][(v + 2) & 7]);
            float hv = bf2f(hr[row * HB + j]);
            float rg = sigm(acc[jt][q] + xr);
            float zg = sigm(acc[2 + jt][q] + xz);
            float ng = tanh_(xn + rg * (acc[4 + jt][q] + bn));
            float hnew = ng + zg * (hv - ng);
            hw[row * HB + j] = f2bf(hnew);
            size_t off = ((size_t)(b0 + row) << 18) + ((size_t)t << 9) + (size_t)dir * 256 + j;
            out[off] = hnew;
            if (s == T_ - 1)
                out[OUT_MAIN + (size_t)dir * B_ * H_ + (size_t)(b0 + row) * H_ + j] = hnew;
        }
    }
    __builtin_amdgcn_sched_barrier(0);
    asm volatile("s_waitcnt lgkmcnt(0)");
    __builtin_amdgcn_s_barrier();
    __builtin_amdgcn_sched_barrier(0);
}

__global__ __launch_bounds__(512, 2) void k_recur(
    const float* __restrict__ whh_f, const float* __restrict__ whh_b,
    const float* __restrict__ bhh_f, const float* __restrict__ bhh_b,
    const unsigned short* __restrict__ XT,
    float* __restrict__ out)
{
    __shared__ __align__(16) unsigned short hb[2 * 16 * HB];
    const int tid = threadIdx.x, lane = tid & 63, wid = tid >> 6;
    const int bid = blockIdx.x;
    const int dir = bid >> 3, b0 = (bid & 7) * 16;
    const float* whh = dir ? whh_b : whh_f;
    const float* bhh = dir ? bhh_b : bhh_f;

    // stationary w_hh fragments: 48 x s16x8 = 192 regs/lane
    s16x8 fB[6][8];
#pragma unroll
    for (int g = 0; g < 3; ++g) {
#pragma unroll
        for (int half = 0; half < 2; ++half) {
            int nt = 2 * g + half;
            int cb = g * 256 + 32 * wid + half * 16;
#pragma unroll
            for (int k0 = 0; k0 < 8; ++k0) {
                const float* sp = whh + (size_t)(cb + (lane & 15)) * H_ + k0 * 32 + (lane >> 4) * 8;
                float fv[8];
                *(f32x4*)&fv[0] = *(const f32x4*)(sp);
                *(f32x4*)&fv[4] = *(const f32x4*)(sp + 4);
                fB[nt][k0] = pack8(fv);
            }
        }
    }
    const float bhn0 = bhh[512 + 32 * wid + (lane & 15)];
    const float bhn1 = bhh[512 + 32 * wid + 16 + (lane & 15)];

    for (int i = tid; i < 16 * HB / 2; i += 512) ((uint32_t*)hb)[i] = 0;
    __syncthreads();

    const unsigned short* XTw = XT + (size_t)bid * T_ * XT_STRIDE;
    s16x8 XA[3], XB[3];
    {   // prologue: load xT(t(0))
        const int t0 = dir ? (T_ - 1) : 0;
        const s16x8* p = (const s16x8*)(XTw + (size_t)t0 * XT_STRIDE) + (size_t)tid * 3;
        XA[0] = p[0]; XA[1] = p[1]; XA[2] = p[2];
    }
#pragma unroll 1
    for (int s = 0; s < T_; s += 2) {
        gru_step<0>(s,     dir, b0, tid, lane, wid, XTw, out, hb, fB, bhn0, bhn1, XA, XB);
        gru_step<1>(s + 1, dir, b0, tid, lane, wid, XTw, out, hb, fB, bhn0, bhn1, XB, XA);
    }
}

extern "C" void kernel_launch(void* const* d_in, const int* in_sizes, int n_in,
                              void* d_out, int out_size, void* d_ws, size_t ws_size,
                              hipStream_t stream) {
    const float* x     = (const float*)d_in[0];
    const float* wih_f = (const float*)d_in[1];
    const float* whh_f = (const float*)d_in[2];
    const float* bih_f = (const float*)d_in[3];
    const float* bhh_f = (const float*)d_in[4];
    const float* wih_b = (const float*)d_in[5];
    const float* whh_b = (const float*)d_in[6];
    const float* bih_b = (const float*)d_in[7];
    const float* bhh_b = (const float*)d_in[8];
    float* out = (float*)d_out;

    unsigned short* wbf = (unsigned short*)d_ws;
    unsigned short* XT  = (unsigned short*)((char*)d_ws + 786432);

    k_convert<<<dim3(768), dim3(512), 0, stream>>>(wih_f, wih_b, wbf);
    k_xgemm<<<dim3(512, 8), dim3(512), 0, stream>>>(x, wbf, bih_f, bhh_f, bih_b, bhh_b, XT);
    k_recur<<<dim3(16), dim3(512), 0, stream>>>(whh_f, whh_b, bhh_f, bhh_b, XT, out);
}